// Round 2
// baseline (494.354 us; speedup 1.0000x reference)
//
#include <hip/hip_runtime.h>
#include <hip/hip_bf16.h>
#include <math.h>

#define B_ROWS 1024
#define DDIM   512
#define CN     51332
#define CPAD   51456   /* 402 * 128 */
#define EPSF   1e-3f
#define SCALE  64.0f
#define NT     8       /* K-steps of 64 */

typedef unsigned short ushort_t;
typedef short bf16x8 __attribute__((ext_vector_type(8)));   // 8 bf16 (4 VGPRs)
typedef float f32x4  __attribute__((ext_vector_type(4)));   // 4 fp32 acc
typedef unsigned short us8 __attribute__((ext_vector_type(8)));
typedef unsigned short us4 __attribute__((ext_vector_type(4)));

static __device__ __forceinline__ unsigned short f2bf(float f) {
    // round-to-nearest-even fp32 -> bf16 (inputs are finite)
    unsigned int u = __float_as_uint(f);
    u += 0x7fffu + ((u >> 16) & 1u);
    return (unsigned short)(u >> 16);
}

// ---------------------------------------------------------------------------
// Pass 1: column sum-of-squares partials + bf16 cast + transpose to [CPAD, DDIM]
// float4 loads (16 B/lane), 4 cols x 64 d per thread in 4 groups of 16 loads:
// ~16 KB outstanding per wave >> the ~9 KB/CU needed to hide HBM latency.
// Each block writes full 128-B kbT row spans (no cross-block partial lines).
__global__ void colpass(const float* __restrict__ kern, ushort_t* __restrict__ kbT,
                        float* __restrict__ partials) {
    const int c4 = (blockIdx.x * 256 + threadIdx.x) * 4;
    if (c4 >= CPAD) return;
    const int d0 = blockIdx.y * 64;
    const bool valid = (c4 < CN);            // CN % 4 == 0 -> per-thread uniform
    float s0 = 0.f, s1 = 0.f, s2 = 0.f, s3 = 0.f;
#pragma unroll
    for (int g = 0; g < 4; ++g) {            // 4 groups of 16 d-rows
        float4 v[16];
#pragma unroll
        for (int j = 0; j < 16; ++j)
            v[j] = valid ? *(const float4*)&kern[(size_t)(d0 + g * 16 + j) * CN + c4]
                         : make_float4(0.f, 0.f, 0.f, 0.f);
        us8 p[4][2];                          // [col][which 8-d chunk]
#pragma unroll
        for (int j = 0; j < 16; ++j) {
            s0 += v[j].x * v[j].x; s1 += v[j].y * v[j].y;
            s2 += v[j].z * v[j].z; s3 += v[j].w * v[j].w;
            p[0][j >> 3][j & 7] = f2bf(v[j].x);
            p[1][j >> 3][j & 7] = f2bf(v[j].y);
            p[2][j >> 3][j & 7] = f2bf(v[j].z);
            p[3][j >> 3][j & 7] = f2bf(v[j].w);
        }
#pragma unroll
        for (int cc = 0; cc < 4; ++cc) {
            *(us8*)&kbT[(size_t)(c4 + cc) * DDIM + d0 + g * 16]     = p[cc][0];
            *(us8*)&kbT[(size_t)(c4 + cc) * DDIM + d0 + g * 16 + 8] = p[cc][1];
        }
    }
    *(float4*)&partials[(size_t)blockIdx.y * CPAD + c4] = make_float4(s0, s1, s2, s3);
}

__global__ void finnorm(const float* __restrict__ partials, float* __restrict__ inv_norm) {
    const int c = blockIdx.x * 256 + threadIdx.x;
    float s = 0.f;
#pragma unroll
    for (int k = 0; k < 8; ++k) s += partials[(size_t)k * CPAD + c];
    inv_norm[c] = 1.0f / fmaxf(sqrtf(s), 1e-5f);
}

__global__ void embcast(const float* __restrict__ emb, ushort_t* __restrict__ embb) {
    const int t = blockIdx.x * 256 + threadIdx.x;    // 4 elems/thread
    const float4 v = ((const float4*)emb)[t];
    us4 o; o[0] = f2bf(v.x); o[1] = f2bf(v.y); o[2] = f2bf(v.z); o[3] = f2bf(v.w);
    *(us4*)&embb[(size_t)t * 4] = o;
}

// ---------------------------------------------------------------------------
// 256x128 counted-vmcnt bf16 MFMA GEMM (m201-faithful register budget).
//   - BM=256, BN=128, BK=64, 8 waves (4m x 2n), per-wave 64x64, acc[4][4]=64 VGPR.
//     a[4][2]+b0+b1 = 64 VGPR -> ~165 total, far from the 256 spill cliff
//     (round-1's 256x256 kept a[8][2] live = ~250 VGPR, likely spilling).
//   - LDS 96 KiB: A[2][256][64] | B[2][128][64]; 1608 blocks -> 7 generations
//     vs 804-block/4-gen (+27% tail) before.
//   - 2 phases/K-step, 16 MFMA each; stages: p0: B(t+1)->next buf (its last
//     reader finished at t-1 p1, barrier-separated); p1: A(t+2)->cur buf
//     (A fully consumed in p0). vmcnt(4) once per K-step retires exactly
//     A(t+1)x4 + B(t+1)x2 (FIFO), leaving A(t+2)x4 in flight. Never vmcnt(0).
//   - Both-sides chunk-XOR swizzle: linear DMA dest, pre-swizzled global
//     source chunk (c8^r8), ds_read XORs chunk^(row&7) -> conflict-free b128.
#define MFMA(d, va, vb) (d) = __builtin_amdgcn_mfma_f32_16x16x32_bf16((va), (vb), (d), 0, 0, 0)

#define STAGE16(gp, lp) __builtin_amdgcn_global_load_lds( \
    (__attribute__((address_space(1))) void*)(gp), \
    (__attribute__((address_space(3))) void*)(lp), 16, 0, 0)

// gl: per-lane global base (row r8, swizzled chunk); sb: LDS ushort base.
// One call stages 128 rows (16 rows/wave): rows half*128? -> here rb = w*16 (+8).
#define STAGE(gl, sb, half, kstep) do { \
    const int rb_ = (half) * 128 + w * 16; \
    STAGE16((gl) + (size_t)rb_ * DDIM + (size_t)(kstep) * 64, &(sb)[rb_ * 64]); \
    STAGE16((gl) + (size_t)(rb_ + 8) * DDIM + (size_t)(kstep) * 64, &(sb)[(rb_ + 8) * 64]); \
} while (0)

__global__ __launch_bounds__(512, 2) void gemm_kernel(
        const ushort_t* __restrict__ embb, const ushort_t* __restrict__ kbT,
        const float* __restrict__ inv_norm, float* __restrict__ out) {
    __shared__ ushort_t smem[49152];    // 96 KB: A[2][16384] | B[2][8192] (ushorts)

    const int tid  = threadIdx.x;
    const int lane = tid & 63;
    const int w    = tid >> 6;                 // wave 0..7
    const int wm = w >> 1, wn = w & 1;         // 4m x 2n wave grid
    const int lm = lane & 15, lq = lane >> 4;  // MFMA row-sel / quad
    const int r8 = lane >> 3, c8 = lane & 7;   // staging lane -> (row, 16B chunk)

    // exact XCD swizzle: 1608 = 8 x 201; m-fast so 4 consecutive blocks in an
    // XCD share one B-panel (128 KB << 4 MB XCD L2).
    const int bid = blockIdx.x;
    const int u   = (bid & 7) * 201 + (bid >> 3);
    const int m0  = (u & 3) * 256;
    const int n0  = (u >> 2) * 128;            // 0..401 tiles

    // per-lane staging source pointers (chunk pre-swizzled with c8^r8)
    const ushort_t* gAl = embb + (size_t)(m0 + r8) * DDIM + ((c8 ^ r8) << 3);
    const ushort_t* gBl = kbT  + (size_t)(n0 + r8) * DDIM + ((c8 ^ r8) << 3);
    // ds_read: LDS[row][cl] holds global chunk cl^(row&7); want chunk lq / lq+4
    const int swz = lm & 7;
    const int ca0 = ((lq    ) ^ swz) << 3;
    const int ca1 = ((lq + 4) ^ swz) << 3;
    const int offA = (wm * 64 + lm) * 64;
    const int offB = (wn * 64 + lm) * 64;

    f32x4 acc[4][4];
#pragma unroll
    for (int i = 0; i < 4; ++i)
#pragma unroll
        for (int j = 0; j < 4; ++j) acc[i][j] = (f32x4){0.f, 0.f, 0.f, 0.f};

    ushort_t* A0 = smem;             // A bufs: 16384 ushorts each
    ushort_t* A1 = smem + 16384;
    ushort_t* B0 = smem + 32768;     // B bufs: 8192 ushorts each
    ushort_t* B1 = smem + 40960;

    // prologue FIFO: [A0 x4, B0 x2, A1 x4] = 10 loads; vmcnt(4) retires A0,B0.
    STAGE(gAl, A0, 0, 0); STAGE(gAl, A0, 1, 0);
    STAGE(gBl, B0, 0, 0);
    STAGE(gAl, A1, 0, 1); STAGE(gAl, A1, 1, 1);
    asm volatile("s_waitcnt vmcnt(4)" ::: "memory");
    __builtin_amdgcn_s_barrier();
    __builtin_amdgcn_sched_barrier(0);

    bf16x8 a[4][2], b0[2][2], b1[2][2];

    for (int t = 0; t < NT; ++t) {
        const int cur = t & 1;
        ushort_t* Sa  = (cur == 0) ? A0 : A1;
        ushort_t* Sb  = (cur == 0) ? B0 : B1;
        ushort_t* SbN = (cur == 0) ? B1 : B0;
        const int kA = (t + 2) & 7;   // wrapped near the end: harmless restage,
        const int kB = (t + 1) & 7;   // keeps vmcnt counts uniform

        // ---- phase 0: ds-read all-A + B[j0,j1] | stage B(t+1)->next | MFMA j0-1
#pragma unroll
        for (int i = 0; i < 4; ++i) {
            a[i][0] = *(const bf16x8*)&Sa[offA + i * 1024 + ca0];
            a[i][1] = *(const bf16x8*)&Sa[offA + i * 1024 + ca1];
        }
#pragma unroll
        for (int j = 0; j < 2; ++j) {
            b0[j][0] = *(const bf16x8*)&Sb[offB + j * 1024 + ca0];
            b0[j][1] = *(const bf16x8*)&Sb[offB + j * 1024 + ca1];
        }
        STAGE(gBl, SbN, 0, kB);
        __builtin_amdgcn_s_barrier();
        __builtin_amdgcn_s_setprio(1);
#pragma unroll
        for (int i = 0; i < 4; ++i)
#pragma unroll
            for (int j = 0; j < 2; ++j) {
                MFMA(acc[i][j], a[i][0], b0[j][0]);
                MFMA(acc[i][j], a[i][1], b0[j][1]);
            }
        __builtin_amdgcn_s_setprio(0);
        __builtin_amdgcn_s_barrier();
        __builtin_amdgcn_sched_barrier(0);

        // ---- phase 1: ds-read B[j2,j3] | stage A(t+2)->cur | MFMA j2-3 | vmcnt(4)
#pragma unroll
        for (int j = 0; j < 2; ++j) {
            b1[j][0] = *(const bf16x8*)&Sb[offB + (j + 2) * 1024 + ca0];
            b1[j][1] = *(const bf16x8*)&Sb[offB + (j + 2) * 1024 + ca1];
        }
        STAGE(gAl, Sa, 0, kA); STAGE(gAl, Sa, 1, kA);
        __builtin_amdgcn_s_barrier();
        __builtin_amdgcn_s_setprio(1);
#pragma unroll
        for (int i = 0; i < 4; ++i)
#pragma unroll
            for (int j = 0; j < 2; ++j) {
                MFMA(acc[i][j + 2], a[i][0], b1[j][0]);
                MFMA(acc[i][j + 2], a[i][1], b1[j][1]);
            }
        __builtin_amdgcn_s_setprio(0);
        asm volatile("s_waitcnt vmcnt(4)" ::: "memory");
        __builtin_amdgcn_s_barrier();
        __builtin_amdgcn_sched_barrier(0);
    }

    // ---- epilogue: drain DMA, wave-private swizzled LDS staging (4 KiB/wave,
    // no barriers: cross-lane within one wave only) -> coalesced 16B stores.
    asm volatile("s_waitcnt vmcnt(0)" ::: "memory");
    __syncthreads();

    float invn[4];
#pragma unroll
    for (int j = 0; j < 4; ++j) {
        const int col = n0 + wn * 64 + j * 16 + lm;
        invn[j] = (col < CN) ? inv_norm[col] : 0.f;
    }
    float* Ew = (float*)smem + w * 1024;        // 16 x 64 f32, swizzled
    const int rr = lane >> 4, cc = lane & 15;
#pragma unroll
    for (int i = 0; i < 4; ++i) {
#pragma unroll
        for (int j = 0; j < 4; ++j)
#pragma unroll
            for (int r = 0; r < 4; ++r) {
                const int row = lq * 4 + r;                     // 0..15
                const int cs  = ((j * 16 + lm) + row * 4) & 63; // swizzle
                float v = acc[i][j][r] * invn[j];
                v = fminf(fmaxf(v, -(1.0f - EPSF)), 1.0f - EPSF) * SCALE;
                Ew[row * 64 + cs] = v;
            }
#pragma unroll
        for (int rep = 0; rep < 4; ++rep) {
            const int row = rep * 4 + rr;                       // 0..15
            const f32x4 v = *(const f32x4*)&Ew[row * 64 + ((cc + row) & 15) * 4];
            const int grow = m0 + wm * 64 + i * 16 + row;
            const int gcol = n0 + wn * 64 + cc * 4;
            if (gcol < CN)                                      // CN%4==0: all-or-nothing
                *(f32x4*)&out[(size_t)grow * CN + gcol] = v;
        }
    }
}

// Label-column fixup: arccos margin path on exactly B_ROWS elements
__global__ void fixup(const float* __restrict__ norms, const int* __restrict__ label,
                      float* __restrict__ out) {
    const int b = blockIdx.x * 256 + threadIdx.x;
    if (b >= B_ROWS) return;
    const int c = label[b];
    const float safe = fminf(fmaxf(norms[b], 1e-3f), 100.0f);
    const float ms = fminf(fmaxf(safe / (100.0f + 1e-3f) * 0.333f, -1.0f), 1.0f);
    const size_t idx = (size_t)b * CN + c;
    const float cosv = out[idx] * (1.0f / SCALE);        // recover clipped cosine
    float theta = acosf(cosv) + 0.5f * ms;               // + M*ms at label
    theta = fminf(fmaxf(theta, EPSF), 3.14159265358979f - EPSF);
    out[idx] = (cosf(theta) - (0.5f - 0.5f * ms)) * SCALE;  // - (HEAD_B - M*ms), * S
}

extern "C" void kernel_launch(void* const* d_in, const int* in_sizes, int n_in,
                              void* d_out, int out_size, void* d_ws, size_t ws_size,
                              hipStream_t stream) {
    const float* emb   = (const float*)d_in[0];
    const float* norms = (const float*)d_in[1];
    const float* kern  = (const float*)d_in[2];
    const int*   label = (const int*)d_in[3];
    float* out = (float*)d_out;

    char* ws = (char*)d_ws;
    ushort_t* kbT = (ushort_t*)ws;                           // CPAD*DDIM*2 = 52,690,944 B
    size_t off = (size_t)CPAD * DDIM * 2;
    ushort_t* embb = (ushort_t*)(ws + off); off += (size_t)B_ROWS * DDIM * 2;
    float* inv_norm = (float*)(ws + off);   off += (size_t)CPAD * 4;
    float* partials = (float*)(ws + off);   // 8*CPAD*4 B ; total ~55.6 MB

    colpass<<<dim3((CPAD / 4 + 255) / 256, 8), 256, 0, stream>>>(kern, kbT, partials);
    embcast<<<dim3((B_ROWS * DDIM / 4) / 256), 256, 0, stream>>>(emb, embb);
    finnorm<<<dim3(CPAD / 256), 256, 0, stream>>>(partials, inv_norm);
    gemm_kernel<<<dim3(1608), 512, 0, stream>>>(embb, kbT, inv_norm, out);
    fixup<<<dim3(B_ROWS / 256 + 1), 256, 0, stream>>>(norms, label, out);
}

// Round 3
// 391.517 us; speedup vs baseline: 1.2627x; 1.2627x over previous
//
#include <hip/hip_runtime.h>
#include <hip/hip_bf16.h>
#include <math.h>

#define B_ROWS 1024
#define DDIM   512
#define CN     51332
#define CPAD   51456   /* 402 * 128 */
#define EPSF   1e-3f
#define SCALE  64.0f
#define NT     8       /* K-steps of 64 */

typedef unsigned short ushort_t;
typedef short bf16x8 __attribute__((ext_vector_type(8)));   // 8 bf16 (4 VGPRs)
typedef float f32x4  __attribute__((ext_vector_type(4)));   // 4 fp32 acc
typedef unsigned short us8 __attribute__((ext_vector_type(8)));
typedef unsigned short us4 __attribute__((ext_vector_type(4)));

static __device__ __forceinline__ unsigned short f2bf(float f) {
    // round-to-nearest-even fp32 -> bf16 (inputs are finite)
    unsigned int u = __float_as_uint(f);
    u += 0x7fffu + ((u >> 16) & 1u);
    return (unsigned short)(u >> 16);
}

// ---------------------------------------------------------------------------
// Pass 1: column sum-of-squares partials + bf16 cast + LDS-transpose to
// [CPAD, DDIM]. Round-2 version died on scattered 16B stores (4 KB lane
// stride -> 2x write amplification, 1.3 TB/s) and serialized loads (VGPR=64).
// Now: 64 cols x 256 d tile via 32 KB LDS.
//   load : lane = col -> 256 B contiguous wave segments, 32 loads in flight.
//   store: half-wave = one col's 512 B d-segment -> contiguous full lines.
//   LDS  : chunk-XOR swizzle (cj ^ col) both sides -> conflict-free b128.
__global__ __launch_bounds__(256) void colpass(const float* __restrict__ kern,
        ushort_t* __restrict__ kbT, float* __restrict__ partials) {
    __shared__ ushort_t tile[64 * 256];        // [col][d-chunk swizzled], 32 KB
    const int c0 = blockIdx.x * 64;
    const int d0 = blockIdx.y * 256;
    const int t  = threadIdx.x;
    const int colL = t & 63;
    const int dg   = t >> 6;                   // 0..3 (== wave id; uniform/wave)
    const int gcol = c0 + colL;
    const bool valid = gcol < CN;
    const int swz = colL & 31;
    float s = 0.f;
#pragma unroll
    for (int h = 0; h < 2; ++h) {
        float v[32];
        const int dh = d0 + dg * 64 + h * 32;
#pragma unroll
        for (int j = 0; j < 32; ++j)
            v[j] = valid ? kern[(size_t)(dh + j) * CN + gcol] : 0.f;
#pragma unroll
        for (int jj = 0; jj < 4; ++jj) {
            us8 pk;
#pragma unroll
            for (int e = 0; e < 8; ++e) {
                const float x = v[jj * 8 + e];
                s += x * x;
                pk[e] = f2bf(x);
            }
            const int cj = dg * 8 + h * 4 + jj;            // 16B chunk, 0..31
            *(us8*)&tile[colL * 256 + ((cj ^ swz) << 3)] = pk;
        }
    }
    partials[(size_t)(blockIdx.y * 4 + dg) * CPAD + gcol] = s;
    __syncthreads();
    const int lane = t & 63;
    const int u = lane & 31, ch = lane >> 5;   // chunk / which col of the pair
#pragma unroll
    for (int p = 0; p < 8; ++p) {
        const int cl = p * 8 + dg * 2 + ch;    // col 0..63
        const us8 val = *(const us8*)&tile[cl * 256 + ((u ^ (cl & 31)) << 3)];
        *(us8*)&kbT[(size_t)(c0 + cl) * DDIM + d0 + u * 8] = val;
    }
}

__global__ void finnorm(const float* __restrict__ partials, float* __restrict__ inv_norm) {
    const int c = blockIdx.x * 256 + threadIdx.x;
    float s = 0.f;
#pragma unroll
    for (int k = 0; k < 8; ++k) s += partials[(size_t)k * CPAD + c];
    inv_norm[c] = 1.0f / fmaxf(sqrtf(s), 1e-5f);
}

__global__ void embcast(const float* __restrict__ emb, ushort_t* __restrict__ embb) {
    const int t = blockIdx.x * 256 + threadIdx.x;    // 4 elems/thread
    const float4 v = ((const float4*)emb)[t];
    us4 o; o[0] = f2bf(v.x); o[1] = f2bf(v.y); o[2] = f2bf(v.z); o[3] = f2bf(v.w);
    *(us4*)&embb[(size_t)t * 4] = o;
}

// ---------------------------------------------------------------------------
// 256x128 counted-vmcnt bf16 MFMA GEMM — UNCHANGED from round 2 (accounting
// puts it at ~48 us, near its composed roofline: ~264 MB traffic / 53.8 GFLOP).
#define MFMA(d, va, vb) (d) = __builtin_amdgcn_mfma_f32_16x16x32_bf16((va), (vb), (d), 0, 0, 0)

#define STAGE16(gp, lp) __builtin_amdgcn_global_load_lds( \
    (__attribute__((address_space(1))) void*)(gp), \
    (__attribute__((address_space(3))) void*)(lp), 16, 0, 0)

#define STAGE(gl, sb, half, kstep) do { \
    const int rb_ = (half) * 128 + w * 16; \
    STAGE16((gl) + (size_t)rb_ * DDIM + (size_t)(kstep) * 64, &(sb)[rb_ * 64]); \
    STAGE16((gl) + (size_t)(rb_ + 8) * DDIM + (size_t)(kstep) * 64, &(sb)[(rb_ + 8) * 64]); \
} while (0)

__global__ __launch_bounds__(512, 2) void gemm_kernel(
        const ushort_t* __restrict__ embb, const ushort_t* __restrict__ kbT,
        const float* __restrict__ inv_norm, float* __restrict__ out) {
    __shared__ ushort_t smem[49152];    // 96 KB: A[2][16384] | B[2][8192] (ushorts)

    const int tid  = threadIdx.x;
    const int lane = tid & 63;
    const int w    = tid >> 6;                 // wave 0..7
    const int wm = w >> 1, wn = w & 1;         // 4m x 2n wave grid
    const int lm = lane & 15, lq = lane >> 4;  // MFMA row-sel / quad
    const int r8 = lane >> 3, c8 = lane & 7;   // staging lane -> (row, 16B chunk)

    const int bid = blockIdx.x;
    const int u   = (bid & 7) * 201 + (bid >> 3);
    const int m0  = (u & 3) * 256;
    const int n0  = (u >> 2) * 128;            // 0..401 tiles

    const ushort_t* gAl = embb + (size_t)(m0 + r8) * DDIM + ((c8 ^ r8) << 3);
    const ushort_t* gBl = kbT  + (size_t)(n0 + r8) * DDIM + ((c8 ^ r8) << 3);
    const int swz = lm & 7;
    const int ca0 = ((lq    ) ^ swz) << 3;
    const int ca1 = ((lq + 4) ^ swz) << 3;
    const int offA = (wm * 64 + lm) * 64;
    const int offB = (wn * 64 + lm) * 64;

    f32x4 acc[4][4];
#pragma unroll
    for (int i = 0; i < 4; ++i)
#pragma unroll
        for (int j = 0; j < 4; ++j) acc[i][j] = (f32x4){0.f, 0.f, 0.f, 0.f};

    ushort_t* A0 = smem;             // A bufs: 16384 ushorts each
    ushort_t* A1 = smem + 16384;
    ushort_t* B0 = smem + 32768;     // B bufs: 8192 ushorts each
    ushort_t* B1 = smem + 40960;

    // prologue FIFO: [A0 x4, B0 x2, A1 x4] = 10 loads; vmcnt(4) retires A0,B0.
    STAGE(gAl, A0, 0, 0); STAGE(gAl, A0, 1, 0);
    STAGE(gBl, B0, 0, 0);
    STAGE(gAl, A1, 0, 1); STAGE(gAl, A1, 1, 1);
    asm volatile("s_waitcnt vmcnt(4)" ::: "memory");
    __builtin_amdgcn_s_barrier();
    __builtin_amdgcn_sched_barrier(0);

    bf16x8 a[4][2], b0[2][2], b1[2][2];

    for (int t = 0; t < NT; ++t) {
        const int cur = t & 1;
        ushort_t* Sa  = (cur == 0) ? A0 : A1;
        ushort_t* Sb  = (cur == 0) ? B0 : B1;
        ushort_t* SbN = (cur == 0) ? B1 : B0;
        const int kA = (t + 2) & 7;   // wrapped near the end: harmless restage,
        const int kB = (t + 1) & 7;   // keeps vmcnt counts uniform

        // ---- phase 0: ds-read all-A + B[j0,j1] | stage B(t+1)->next | MFMA j0-1
#pragma unroll
        for (int i = 0; i < 4; ++i) {
            a[i][0] = *(const bf16x8*)&Sa[offA + i * 1024 + ca0];
            a[i][1] = *(const bf16x8*)&Sa[offA + i * 1024 + ca1];
        }
#pragma unroll
        for (int j = 0; j < 2; ++j) {
            b0[j][0] = *(const bf16x8*)&Sb[offB + j * 1024 + ca0];
            b0[j][1] = *(const bf16x8*)&Sb[offB + j * 1024 + ca1];
        }
        STAGE(gBl, SbN, 0, kB);
        __builtin_amdgcn_s_barrier();
        __builtin_amdgcn_s_setprio(1);
#pragma unroll
        for (int i = 0; i < 4; ++i)
#pragma unroll
            for (int j = 0; j < 2; ++j) {
                MFMA(acc[i][j], a[i][0], b0[j][0]);
                MFMA(acc[i][j], a[i][1], b0[j][1]);
            }
        __builtin_amdgcn_s_setprio(0);
        __builtin_amdgcn_s_barrier();
        __builtin_amdgcn_sched_barrier(0);

        // ---- phase 1: ds-read B[j2,j3] | stage A(t+2)->cur | MFMA j2-3 | vmcnt(4)
#pragma unroll
        for (int j = 0; j < 2; ++j) {
            b1[j][0] = *(const bf16x8*)&Sb[offB + (j + 2) * 1024 + ca0];
            b1[j][1] = *(const bf16x8*)&Sb[offB + (j + 2) * 1024 + ca1];
        }
        STAGE(gAl, Sa, 0, kA); STAGE(gAl, Sa, 1, kA);
        __builtin_amdgcn_s_barrier();
        __builtin_amdgcn_s_setprio(1);
#pragma unroll
        for (int i = 0; i < 4; ++i)
#pragma unroll
            for (int j = 0; j < 2; ++j) {
                MFMA(acc[i][j + 2], a[i][0], b1[j][0]);
                MFMA(acc[i][j + 2], a[i][1], b1[j][1]);
            }
        __builtin_amdgcn_s_setprio(0);
        asm volatile("s_waitcnt vmcnt(4)" ::: "memory");
        __builtin_amdgcn_s_barrier();
        __builtin_amdgcn_sched_barrier(0);
    }

    // ---- epilogue: drain DMA, wave-private swizzled LDS staging (4 KiB/wave,
    // no barriers: cross-lane within one wave only) -> coalesced 16B stores.
    asm volatile("s_waitcnt vmcnt(0)" ::: "memory");
    __syncthreads();

    float invn[4];
#pragma unroll
    for (int j = 0; j < 4; ++j) {
        const int col = n0 + wn * 64 + j * 16 + lm;
        invn[j] = (col < CN) ? inv_norm[col] : 0.f;
    }
    float* Ew = (float*)smem + w * 1024;        // 16 x 64 f32, swizzled
    const int rr = lane >> 4, cc = lane & 15;
#pragma unroll
    for (int i = 0; i < 4; ++i) {
#pragma unroll
        for (int j = 0; j < 4; ++j)
#pragma unroll
            for (int r = 0; r < 4; ++r) {
                const int row = lq * 4 + r;                     // 0..15
                const int cs  = ((j * 16 + lm) + row * 4) & 63; // swizzle
                float v = acc[i][j][r] * invn[j];
                v = fminf(fmaxf(v, -(1.0f - EPSF)), 1.0f - EPSF) * SCALE;
                Ew[row * 64 + cs] = v;
            }
#pragma unroll
        for (int rep = 0; rep < 4; ++rep) {
            const int row = rep * 4 + rr;                       // 0..15
            const f32x4 v = *(const f32x4*)&Ew[row * 64 + ((cc + row) & 15) * 4];
            const int grow = m0 + wm * 64 + i * 16 + row;
            const int gcol = n0 + wn * 64 + cc * 4;
            if (gcol < CN)                                      // CN%4==0: all-or-nothing
                *(f32x4*)&out[(size_t)grow * CN + gcol] = v;
        }
    }
}

// Label-column fixup: arccos margin path on exactly B_ROWS elements
__global__ void fixup(const float* __restrict__ norms, const int* __restrict__ label,
                      float* __restrict__ out) {
    const int b = blockIdx.x * 256 + threadIdx.x;
    if (b >= B_ROWS) return;
    const int c = label[b];
    const float safe = fminf(fmaxf(norms[b], 1e-3f), 100.0f);
    const float ms = fminf(fmaxf(safe / (100.0f + 1e-3f) * 0.333f, -1.0f), 1.0f);
    const size_t idx = (size_t)b * CN + c;
    const float cosv = out[idx] * (1.0f / SCALE);        // recover clipped cosine
    float theta = acosf(cosv) + 0.5f * ms;               // + M*ms at label
    theta = fminf(fmaxf(theta, EPSF), 3.14159265358979f - EPSF);
    out[idx] = (cosf(theta) - (0.5f - 0.5f * ms)) * SCALE;  // - (HEAD_B - M*ms), * S
}

extern "C" void kernel_launch(void* const* d_in, const int* in_sizes, int n_in,
                              void* d_out, int out_size, void* d_ws, size_t ws_size,
                              hipStream_t stream) {
    const float* emb   = (const float*)d_in[0];
    const float* norms = (const float*)d_in[1];
    const float* kern  = (const float*)d_in[2];
    const int*   label = (const int*)d_in[3];
    float* out = (float*)d_out;

    char* ws = (char*)d_ws;
    ushort_t* kbT = (ushort_t*)ws;                           // CPAD*DDIM*2 = 52,690,944 B
    size_t off = (size_t)CPAD * DDIM * 2;
    ushort_t* embb = (ushort_t*)(ws + off); off += (size_t)B_ROWS * DDIM * 2;
    float* inv_norm = (float*)(ws + off);   off += (size_t)CPAD * 4;
    float* partials = (float*)(ws + off);   // 8*CPAD*4 B ; total ~55.6 MB

    colpass<<<dim3(CPAD / 64, 2), 256, 0, stream>>>(kern, kbT, partials);
    embcast<<<dim3((B_ROWS * DDIM / 4) / 256), 256, 0, stream>>>(emb, embb);
    finnorm<<<dim3(CPAD / 256), 256, 0, stream>>>(partials, inv_norm);
    gemm_kernel<<<dim3(1608), 512, 0, stream>>>(embb, kbT, inv_norm, out);
    fixup<<<dim3(B_ROWS / 256 + 1), 256, 0, stream>>>(norms, label, out);
}